// Round 4
// baseline (1121.489 us; speedup 1.0000x reference)
//
#include <hip/hip_runtime.h>
#include <stdint.h>

#define CDIM   4096
#define S_N    3355443
#define R_N    1048576
#define N1     (S_N + R_N)                 // 4404019 contributions
#define TILE   4096
#define NTILES ((N1 + TILE - 1) / TILE)    // 1076
#define NPAD   (NTILES * TILE)             // 4407296
#define NSB    (NPAD / 256)                // 17216
#define NT2    320                         // survivor tiles (1.31M slots, ~24% margin)
#define SPAD   (NT2 * TILE)                // 1310720
#define PAD_KEY 0xFFFFFFu
#define PAD_VAL 0xFFFFFFFFu                // impossible value bits (sums are >= +0)

// Exclusive block-wide scan over 256 threads (4 waves). Contains syncthreads.
static __device__ __forceinline__ unsigned blockScanExcl(unsigned v, unsigned t,
                                                         unsigned* lw, unsigned* tot){
  unsigned lane = t & 63u, w = t >> 6;
  unsigned x = v;
  #pragma unroll
  for (int off = 1; off < 64; off <<= 1){
    unsigned y = __shfl_up(x, off, 64);
    if (lane >= (unsigned)off) x += y;
  }
  if (lane == 63u) lw[w] = x;
  __syncthreads();
  unsigned woff = 0;
  for (unsigned i = 0; i < w; i++) woff += lw[i];
  *tot = lw[0] + lw[1] + lw[2] + lw[3];
  __syncthreads();
  return x + woff - v;
}

__global__ __launch_bounds__(256) void k_zero(unsigned* __restrict__ p, unsigned n){
  unsigned i = blockIdx.x * 256u + threadIdx.x;
  if (i < n) p[i] = 0u;
}

// Build packed contributions: high32 = key, low32 = value bits. Samples first,
// then decayed buffer entries, then padding -> stable sort preserves
// segment_sum's accumulation order exactly.
__global__ __launch_bounds__(256) void k_build(const int* __restrict__ sidx,
                                               const int* __restrict__ ridx,
                                               const float* __restrict__ rval,
                                               const float* __restrict__ grad,
                                               uint64_t* __restrict__ A){
  unsigned i = blockIdx.x * 256u + threadIdx.x;
  uint32_t key, vb;
  if (i < S_N){
    key = (uint32_t)sidx[i];
    vb  = __float_as_uint(fabsf(grad[i]));
  } else if (i < N1){
    unsigned j = i - S_N;
    key = (uint32_t)(ridx[2u*j] * CDIM + ridx[2u*j + 1u]);
    const float ADJF = (float)(1.0 - (3355443.0 / 16777216.0) * (1.0 - 0.95));
    vb = __float_as_uint(ADJF * rval[j]);
  } else {
    key = PAD_KEY; vb = PAD_VAL;
  }
  A[i] = ((uint64_t)key << 32) | (uint64_t)vb;
}

// Per-tile 256-bin histogram of digit (e >> shift) & 0xFF. Layout [digit][tile].
__global__ __launch_bounds__(256) void k_hist(const uint64_t* __restrict__ in, unsigned shift,
                                              unsigned* __restrict__ gh, unsigned nt){
  __shared__ unsigned h[256];
  unsigned t = threadIdx.x;
  h[t] = 0; __syncthreads();
  size_t base = (size_t)blockIdx.x * TILE;
  #pragma unroll
  for (int r = 0; r < 16; r++){
    uint64_t e = in[base + (size_t)r*256 + t];
    atomicAdd(&h[(unsigned)((e >> shift) & 0xFF)], 1u);
  }
  __syncthreads();
  gh[t * nt + blockIdx.x] = h[t];
}

// Row scan: block d turns gh[d][*] into exclusive tile prefixes + digit total.
__global__ __launch_bounds__(256) void k_scanrows(unsigned* __restrict__ gh,
                                                  unsigned* __restrict__ dtot, unsigned nt){
  __shared__ unsigned lw[4];
  unsigned d = blockIdx.x, t = threadIdx.x;
  unsigned carry = 0;
  for (unsigned base = 0; base < nt; base += 256){
    unsigned i = base + t;
    unsigned v = (i < nt) ? gh[d * nt + i] : 0u;
    unsigned tot;
    unsigned e = blockScanExcl(v, t, lw, &tot);
    if (i < nt) gh[d * nt + i] = e + carry;
    carry += tot;
  }
  if (t == 0) dtot[d] = carry;
}

// ---- LDS-staged stable radix scatter (round-2 proven structure) ----------
template <bool FINAL>
__device__ __forceinline__ void scatter_body(const uint64_t* __restrict__ in,
                                             uint64_t* __restrict__ out,
                                             float* __restrict__ fout,
                                             unsigned shift,
                                             const unsigned* __restrict__ gh,
                                             const unsigned* __restrict__ dtot,
                                             unsigned nt){
  __shared__ unsigned wrun[4*256];
  __shared__ unsigned gput[256];
  __shared__ unsigned lw[4];
  __shared__ uint64_t stage[TILE];       // 32 KB
  unsigned t = threadIdx.x, lane = t & 63u, w = t >> 6;
  wrun[t] = 0; wrun[256+t] = 0; wrun[512+t] = 0; wrun[768+t] = 0;
  __syncthreads();
  uint64_t ltm = (lane == 0) ? 0ull : (~0ull >> (64u - lane));
  uint64_t elems[16]; unsigned rnk[16]; unsigned dg[16];
  size_t base = (size_t)blockIdx.x * TILE + (size_t)w * 1024;
  #pragma unroll
  for (int r = 0; r < 16; r++){
    uint64_t e = in[base + (size_t)r*64 + lane];
    elems[r] = e;
    unsigned d = (unsigned)((e >> shift) & 0xFF);
    uint64_t m = ~0ull;
    #pragma unroll
    for (int b = 0; b < 8; b++){
      uint64_t bb = __ballot((d >> b) & 1u);
      m &= ((d >> b) & 1u) ? bb : ~bb;
    }
    unsigned rr   = (unsigned)__popcll(m & ltm);
    unsigned prev = wrun[w*256 + d];
    __builtin_amdgcn_wave_barrier();
    if (rr == 0) wrun[w*256 + d] = prev + (unsigned)__popcll(m);
    __builtin_amdgcn_wave_barrier();
    rnk[r] = prev + rr;
    dg[r]  = d;
  }
  __syncthreads();
  {
    unsigned d = t;
    unsigned c0 = wrun[d], c1 = wrun[256+d], c2 = wrun[512+d], c3 = wrun[768+d];
    unsigned cnt = c0 + c1 + c2 + c3;
    unsigned tot, tot2;
    unsigned ldig  = blockScanExcl(cnt, t, lw, &tot);
    unsigned dbase = blockScanExcl(dtot[d], t, lw, &tot2);
    gput[d] = dbase + gh[d * nt + blockIdx.x] - ldig;
    wrun[d]       = ldig;
    wrun[256 + d] = ldig + c0;
    wrun[512 + d] = ldig + c0 + c1;
    wrun[768 + d] = ldig + c0 + c1 + c2;
  }
  __syncthreads();
  #pragma unroll
  for (int r = 0; r < 16; r++)
    stage[ wrun[w*256 + dg[r]] + rnk[r] ] = elems[r];
  __syncthreads();
  #pragma unroll
  for (int r = 0; r < 16; r++){
    unsigned j = (unsigned)r * 256u + t;
    uint64_t e = stage[j];
    unsigned d = (unsigned)((e >> shift) & 0xFF);
    unsigned dest = gput[d] + j;
    if (FINAL){
      if (dest < R_N){
        uint32_t key = (uint32_t)(e >> 32);
        fout[2u*dest]        = (float)(key >> 12);
        fout[2u*dest + 1u]   = (float)(key & 4095u);
        fout[2u*R_N + dest]  = __uint_as_float(~(uint32_t)e);
      }
    } else {
      out[dest] = e;
    }
  }
}

__global__ __launch_bounds__(256) void k_scatter(const uint64_t* __restrict__ in,
                                                 uint64_t* __restrict__ out,
                                                 unsigned shift,
                                                 const unsigned* __restrict__ gh,
                                                 const unsigned* __restrict__ dtot,
                                                 unsigned nt){
  scatter_body<false>(in, out, nullptr, shift, gh, dtot, nt);
}

__global__ __launch_bounds__(256) void k_scatter_out(const uint64_t* __restrict__ in,
                                                     float* __restrict__ fout,
                                                     unsigned shift,
                                                     const unsigned* __restrict__ gh,
                                                     const unsigned* __restrict__ dtot,
                                                     unsigned nt){
  scatter_body<true>(in, nullptr, fout, shift, gh, dtot, nt);
}

// Count real segment heads per 256-elem block (pad heads excluded -> total = U).
__global__ __launch_bounds__(256) void k_headcount(const uint64_t* __restrict__ in,
                                                   unsigned* __restrict__ hcnt){
  __shared__ unsigned wc[4];
  unsigned t = threadIdx.x, lane = t & 63u, w = t >> 6;
  size_t p = (size_t)blockIdx.x * 256 + t;
  uint64_t e = in[p];
  uint32_t k = (uint32_t)(e >> 32);
  bool head = ((p == 0) || ((uint32_t)(in[p-1] >> 32) != k)) && ((uint32_t)e != PAD_VAL);
  uint64_t m = __ballot(head);
  if (lane == 0) wc[w] = (unsigned)__popcll(m);
  __syncthreads();
  if (t == 0) hcnt[blockIdx.x] = wc[0] + wc[1] + wc[2] + wc[3];
}

// Fast single-block scan of NSB counts via u16 LDS staging; writes total.
__global__ __launch_bounds__(256) void k_scanheads(unsigned* __restrict__ hcnt,
                                                   unsigned* __restrict__ utot){
  __shared__ unsigned short buf[NSB];    // 34.4 KB
  __shared__ unsigned lw[4];
  unsigned t = threadIdx.x;
  for (unsigned i = t; i < NSB; i += 256) buf[i] = (unsigned short)hcnt[i];
  __syncthreads();
  const unsigned CH = (NSB + 255) / 256;
  unsigned s = 0;
  for (unsigned k = 0; k < CH; k++){
    unsigned i = t * CH + k;
    if (i < NSB) s += buf[i];
  }
  unsigned tot;
  unsigned carry = blockScanExcl(s, t, lw, &tot);
  for (unsigned k = 0; k < CH; k++){
    unsigned i = t * CH + k;
    if (i < NSB){ unsigned v = buf[i]; hcnt[i] = carry; carry += v; }
  }
  if (t == 0) utot[0] = tot;
}

// Sentinel-fill [*utot, grid-extent).
__global__ __launch_bounds__(256) void k_fill_tail(uint64_t* __restrict__ A,
                                                   const unsigned* __restrict__ utot){
  unsigned U = utot[0];
  unsigned i = blockIdx.x * 256u + threadIdx.x;
  if (i >= U) A[i] = ((uint64_t)PAD_KEY << 32) | (uint64_t)PAD_VAL;
}

// In-order segmented sum (fp32, original contribution order -> bit-identical
// to segment_sum). Candidates written dense, key-ascending. Fused: global
// 256-bin histogram of the candidate sortkey's top byte (for radix-select).
__global__ __launch_bounds__(256) void k_segsum(const uint64_t* __restrict__ in,
                                                uint64_t* __restrict__ out,
                                                const unsigned* __restrict__ hbase,
                                                unsigned* __restrict__ h_hi){
  __shared__ unsigned wc[4], woffs[4];
  __shared__ unsigned hh[256];
  unsigned t = threadIdx.x, lane = t & 63u, w = t >> 6;
  hh[t] = 0;
  size_t p = (size_t)blockIdx.x * 256 + t;
  uint64_t e0 = in[p];
  uint32_t k = (uint32_t)(e0 >> 32);
  bool head = ((p == 0) || ((uint32_t)(in[p-1] >> 32) != k)) && ((uint32_t)e0 != PAD_VAL);
  uint64_t m = __ballot(head);
  if (lane == 0) wc[w] = (unsigned)__popcll(m);
  __syncthreads();
  if (t == 0){ unsigned a = 0; for (int i = 0; i < 4; i++){ woffs[i] = a; a += wc[i]; } }
  __syncthreads();
  if (head){
    uint64_t ltm = (lane == 0) ? 0ull : (~0ull >> (64u - lane));
    unsigned rank = (unsigned)__popcll(m & ltm);
    unsigned oidx = hbase[blockIdx.x] + woffs[w] + rank;
    float s = __uint_as_float((uint32_t)e0);
    size_t q = p + 1;
    while (q < NPAD){
      uint64_t e = in[q];
      if ((uint32_t)(e >> 32) != k) break;
      uint32_t vb = (uint32_t)e;
      if (vb == PAD_VAL) break;
      s += __uint_as_float(vb);
      q++;
    }
    uint32_t sk = ~__float_as_uint(s);
    out[oidx] = ((uint64_t)k << 32) | (uint64_t)sk;
    atomicAdd(&hh[sk >> 24], 1u);
  }
  __syncthreads();
  if (hh[t]) atomicAdd(&h_hi[t], hh[t]);
}

// Find b* = smallest top-byte with inclusive-cum >= R (serial 256 iters).
static __device__ __forceinline__ unsigned pick_hi(const unsigned* h_hi, unsigned* cumExcl){
  unsigned cum = 0;
  for (unsigned b = 0; b < 256; b++){
    unsigned c = h_hi[b];
    if (cum + c >= R_N){ *cumExcl = cum; return b; }
    cum += c;
  }
  *cumExcl = cum; return 255u;
}
static __device__ __forceinline__ unsigned pick_thr16(const unsigned* h_hi,
                                                      const unsigned* h_lo){
  unsigned cumB;
  unsigned b = pick_hi(h_hi, &cumB);
  unsigned cum = cumB;
  for (unsigned c = 0; c < 256; c++){
    unsigned v = h_lo[c];
    if (cum + v >= R_N) return (b << 8) | c;
    cum += v;
  }
  return (b << 8) | 255u;
}

// Histogram sortkey bits [16,24) restricted to elements with top byte == b*.
__global__ __launch_bounds__(256) void k_selhist_lo(const uint64_t* __restrict__ A,
                                                    const unsigned* __restrict__ h_hi,
                                                    unsigned* __restrict__ h_lo){
  __shared__ unsigned h[256];
  __shared__ unsigned bstar;
  unsigned t = threadIdx.x;
  h[t] = 0;
  if (t == 0){ unsigned dummy; bstar = pick_hi(h_hi, &dummy); }
  __syncthreads();
  unsigned bs = bstar;
  size_t base = (size_t)blockIdx.x * TILE;
  #pragma unroll
  for (int r = 0; r < 16; r++){
    uint32_t vb = (uint32_t)A[base + (size_t)r*256 + t];
    if ((vb >> 24) == bs) atomicAdd(&h[(vb >> 16) & 0xFFu], 1u);
  }
  __syncthreads();
  if (h[t]) atomicAdd(&h_lo[t], h[t]);
}

// Count survivors (sk16 <= thr16) per 256-elem block.
__global__ __launch_bounds__(256) void k_cmpcount(const uint64_t* __restrict__ A,
                                                  const unsigned* __restrict__ h_hi,
                                                  const unsigned* __restrict__ h_lo,
                                                  unsigned* __restrict__ ccnt){
  __shared__ unsigned wc[4];
  __shared__ unsigned thr;
  unsigned t = threadIdx.x, lane = t & 63u, w = t >> 6;
  if (t == 0) thr = pick_thr16(h_hi, h_lo);
  __syncthreads();
  size_t p = (size_t)blockIdx.x * 256 + t;
  bool q = (((uint32_t)A[p]) >> 16) <= thr;
  uint64_t m = __ballot(q);
  if (lane == 0) wc[w] = (unsigned)__popcll(m);
  __syncthreads();
  if (t == 0) ccnt[blockIdx.x] = wc[0] + wc[1] + wc[2] + wc[3];
}

// Stable compaction of survivors into B[0, M).
__global__ __launch_bounds__(256) void k_compact(const uint64_t* __restrict__ A,
                                                 uint64_t* __restrict__ B,
                                                 const unsigned* __restrict__ h_hi,
                                                 const unsigned* __restrict__ h_lo,
                                                 const unsigned* __restrict__ cbase){
  __shared__ unsigned wc[4], woffs[4];
  __shared__ unsigned thr;
  unsigned t = threadIdx.x, lane = t & 63u, w = t >> 6;
  if (t == 0) thr = pick_thr16(h_hi, h_lo);
  __syncthreads();
  size_t p = (size_t)blockIdx.x * 256 + t;
  uint64_t e = A[p];
  bool q = (((uint32_t)e) >> 16) <= thr;
  uint64_t m = __ballot(q);
  if (lane == 0) wc[w] = (unsigned)__popcll(m);
  __syncthreads();
  if (t == 0){ unsigned a = 0; for (int i = 0; i < 4; i++){ woffs[i] = a; a += wc[i]; } }
  __syncthreads();
  if (q){
    uint64_t ltm = (lane == 0) ? 0ull : (~0ull >> (64u - lane));
    unsigned rank = (unsigned)__popcll(m & ltm);
    B[cbase[blockIdx.x] + woffs[w] + rank] = e;
  }
}

extern "C" void kernel_launch(void* const* d_in, const int* in_sizes, int n_in,
                              void* d_out, int out_size, void* d_ws, size_t ws_size,
                              hipStream_t stream) {
  const int*   sidx = (const int*)d_in[0];
  const int*   ridx = (const int*)d_in[1];
  const float* rval = (const float*)d_in[2];
  const float* grad = (const float*)d_in[3];
  float* out = (float*)d_out;

  uint64_t* A0   = (uint64_t*)d_ws;                       // 35.3 MB
  uint64_t* A1   = A0 + NPAD;                             // 35.3 MB
  unsigned* gh   = (unsigned*)(A1 + NPAD);                // 256*NTILES = 1.1 MB
  unsigned* dtot = gh + 256 * NTILES;                     // 1 KB
  unsigned* hcnt = dtot + 256;                            // 67 KB
  unsigned* utot = hcnt + NSB;                            // 4 B
  unsigned* h_hi = utot + 1;                              // 1 KB
  unsigned* h_lo = h_hi + 256;                            // 1 KB
  unsigned* ccnt = h_lo + 256;                            // 67 KB
  unsigned* mtot = ccnt + NSB;                            // 4 B

  k_zero <<<2, 256, 0, stream>>>(h_hi, 512);              // h_hi + h_lo
  k_build<<<NSB, 256, 0, stream>>>(sidx, ridx, rval, grad, A0);

  // Stable key sort: 24 bits, 3 x 8-bit passes. A0->A1->A0->A1.
  k_hist    <<<NTILES, 256, 0, stream>>>(A0, 32, gh, NTILES);
  k_scanrows<<<256,    256, 0, stream>>>(gh, dtot, NTILES);
  k_scatter <<<NTILES, 256, 0, stream>>>(A0, A1, 32, gh, dtot, NTILES);
  k_hist    <<<NTILES, 256, 0, stream>>>(A1, 40, gh, NTILES);
  k_scanrows<<<256,    256, 0, stream>>>(gh, dtot, NTILES);
  k_scatter <<<NTILES, 256, 0, stream>>>(A1, A0, 40, gh, dtot, NTILES);
  k_hist    <<<NTILES, 256, 0, stream>>>(A0, 48, gh, NTILES);
  k_scanrows<<<256,    256, 0, stream>>>(gh, dtot, NTILES);
  k_scatter <<<NTILES, 256, 0, stream>>>(A0, A1, 48, gh, dtot, NTILES);

  // Coalesce (candidates key-ascending in A0) + fused top-byte histogram.
  k_headcount<<<NSB, 256, 0, stream>>>(A1, hcnt);
  k_scanheads<<<1,   256, 0, stream>>>(hcnt, utot);
  k_fill_tail<<<NSB, 256, 0, stream>>>(A0, utot);
  k_segsum   <<<NSB, 256, 0, stream>>>(A1, A0, hcnt, h_hi);

  // Radix-select on top 16 sortkey bits, then stable compaction to A1[0,M).
  k_selhist_lo<<<NTILES, 256, 0, stream>>>(A0, h_hi, h_lo);
  k_cmpcount  <<<NSB, 256, 0, stream>>>(A0, h_hi, h_lo, ccnt);
  k_scanheads <<<1,   256, 0, stream>>>(ccnt, mtot);
  k_compact   <<<NSB, 256, 0, stream>>>(A0, A1, h_hi, h_lo, ccnt);
  k_fill_tail <<<SPAD/256, 256, 0, stream>>>(A1, mtot);

  // Stable value sort on survivors: 4 x 8-bit passes, final fused with output.
  // A1->A0->A1->A0->out.
  k_hist    <<<NT2, 256, 0, stream>>>(A1, 0, gh, NT2);
  k_scanrows<<<256, 256, 0, stream>>>(gh, dtot, NT2);
  k_scatter <<<NT2, 256, 0, stream>>>(A1, A0, 0, gh, dtot, NT2);
  k_hist    <<<NT2, 256, 0, stream>>>(A0, 8, gh, NT2);
  k_scanrows<<<256, 256, 0, stream>>>(gh, dtot, NT2);
  k_scatter <<<NT2, 256, 0, stream>>>(A0, A1, 8, gh, dtot, NT2);
  k_hist    <<<NT2, 256, 0, stream>>>(A1, 16, gh, NT2);
  k_scanrows<<<256, 256, 0, stream>>>(gh, dtot, NT2);
  k_scatter <<<NT2, 256, 0, stream>>>(A1, A0, 16, gh, dtot, NT2);
  k_hist       <<<NT2, 256, 0, stream>>>(A0, 24, gh, NT2);
  k_scanrows   <<<256, 256, 0, stream>>>(gh, dtot, NT2);
  k_scatter_out<<<NT2, 256, 0, stream>>>(A0, out, 24, gh, dtot, NT2);
}

// Round 5
// 436.994 us; speedup vs baseline: 2.5664x; 2.5664x over previous
//
#include <hip/hip_runtime.h>
#include <stdint.h>

#define CDIM   4096
#define S_N    3355443
#define R_N    1048576
#define N1     (S_N + R_N)                 // 4404019 contributions
#define TILE   4096
#define NTILES ((N1 + TILE - 1) / TILE)    // 1076
#define NPAD   (NTILES * TILE)             // 4407296
#define NSB    (NPAD / 256)                // 17216
#define NT2    320                         // survivor tiles (1.31M slots, ~24% margin)
#define SPAD   (NT2 * TILE)                // 1310720
#define PAD_KEY 0xFFFFFFu
#define PAD_VAL 0xFFFFFFFFu                // impossible raw value bits (inputs are +/fabs)

// Exclusive block-wide scan over 256 threads (4 waves). Contains syncthreads.
static __device__ __forceinline__ unsigned blockScanExcl(unsigned v, unsigned t,
                                                         unsigned* lw, unsigned* tot){
  unsigned lane = t & 63u, w = t >> 6;
  unsigned x = v;
  #pragma unroll
  for (int off = 1; off < 64; off <<= 1){
    unsigned y = __shfl_up(x, off, 64);
    if (lane >= (unsigned)off) x += y;
  }
  if (lane == 63u) lw[w] = x;
  __syncthreads();
  unsigned woff = 0;
  for (unsigned i = 0; i < w; i++) woff += lw[i];
  *tot = lw[0] + lw[1] + lw[2] + lw[3];
  __syncthreads();
  return x + woff - v;
}

// Build packed contributions: high32 = key, low32 = value bits. Samples first,
// then decayed buffer entries, then padding -> stable sort preserves
// segment_sum's accumulation order exactly.
__global__ __launch_bounds__(256) void k_build(const int* __restrict__ sidx,
                                               const int* __restrict__ ridx,
                                               const float* __restrict__ rval,
                                               const float* __restrict__ grad,
                                               uint64_t* __restrict__ A){
  unsigned i = blockIdx.x * 256u + threadIdx.x;
  uint32_t key, vb;
  if (i < S_N){
    key = (uint32_t)sidx[i];
    vb  = __float_as_uint(fabsf(grad[i]));
  } else if (i < N1){
    unsigned j = i - S_N;
    key = (uint32_t)(ridx[2u*j] * CDIM + ridx[2u*j + 1u]);
    const float ADJF = (float)(1.0 - (3355443.0 / 16777216.0) * (1.0 - 0.95));
    vb = __float_as_uint(ADJF * rval[j]);
  } else {
    key = PAD_KEY; vb = PAD_VAL;
  }
  A[i] = ((uint64_t)key << 32) | (uint64_t)vb;
}

// Per-tile 256-bin histogram of digit (e >> shift) & 0xFF. Layout [digit][tile].
// NO global atomics (lesson from round 4).
__global__ __launch_bounds__(256) void k_hist(const uint64_t* __restrict__ in, unsigned shift,
                                              unsigned* __restrict__ gh, unsigned nt){
  __shared__ unsigned h[256];
  unsigned t = threadIdx.x;
  h[t] = 0; __syncthreads();
  size_t base = (size_t)blockIdx.x * TILE;
  #pragma unroll
  for (int r = 0; r < 16; r++){
    uint64_t e = in[base + (size_t)r*256 + t];
    atomicAdd(&h[(unsigned)((e >> shift) & 0xFF)], 1u);
  }
  __syncthreads();
  gh[t * nt + blockIdx.x] = h[t];
}

// Row scan: block d turns gh[d][*] into exclusive tile prefixes + digit total.
__global__ __launch_bounds__(256) void k_scanrows(unsigned* __restrict__ gh,
                                                  unsigned* __restrict__ dtot, unsigned nt){
  __shared__ unsigned lw[4];
  unsigned d = blockIdx.x, t = threadIdx.x;
  unsigned carry = 0;
  for (unsigned base = 0; base < nt; base += 256){
    unsigned i = base + t;
    unsigned v = (i < nt) ? gh[d * nt + i] : 0u;
    unsigned tot;
    unsigned e = blockScanExcl(v, t, lw, &tot);
    if (i < nt) gh[d * nt + i] = e + carry;
    carry += tot;
  }
  if (t == 0) dtot[d] = carry;
}

// ---- LDS-staged stable radix scatter (round-2 proven structure) ----------
template <bool FINAL>
__device__ __forceinline__ void scatter_body(const uint64_t* __restrict__ in,
                                             uint64_t* __restrict__ out,
                                             float* __restrict__ fout,
                                             unsigned shift,
                                             const unsigned* __restrict__ gh,
                                             const unsigned* __restrict__ dtot,
                                             unsigned nt){
  __shared__ unsigned wrun[4*256];
  __shared__ unsigned gput[256];
  __shared__ unsigned lw[4];
  __shared__ uint64_t stage[TILE];       // 32 KB
  unsigned t = threadIdx.x, lane = t & 63u, w = t >> 6;
  wrun[t] = 0; wrun[256+t] = 0; wrun[512+t] = 0; wrun[768+t] = 0;
  __syncthreads();
  uint64_t ltm = (lane == 0) ? 0ull : (~0ull >> (64u - lane));
  uint64_t elems[16]; unsigned rnk[16]; unsigned dg[16];
  size_t base = (size_t)blockIdx.x * TILE + (size_t)w * 1024;
  #pragma unroll
  for (int r = 0; r < 16; r++){
    uint64_t e = in[base + (size_t)r*64 + lane];
    elems[r] = e;
    unsigned d = (unsigned)((e >> shift) & 0xFF);
    uint64_t m = ~0ull;
    #pragma unroll
    for (int b = 0; b < 8; b++){
      uint64_t bb = __ballot((d >> b) & 1u);
      m &= ((d >> b) & 1u) ? bb : ~bb;
    }
    unsigned rr   = (unsigned)__popcll(m & ltm);
    unsigned prev = wrun[w*256 + d];
    __builtin_amdgcn_wave_barrier();
    if (rr == 0) wrun[w*256 + d] = prev + (unsigned)__popcll(m);
    __builtin_amdgcn_wave_barrier();
    rnk[r] = prev + rr;
    dg[r]  = d;
  }
  __syncthreads();
  {
    unsigned d = t;
    unsigned c0 = wrun[d], c1 = wrun[256+d], c2 = wrun[512+d], c3 = wrun[768+d];
    unsigned cnt = c0 + c1 + c2 + c3;
    unsigned tot, tot2;
    unsigned ldig  = blockScanExcl(cnt, t, lw, &tot);
    unsigned dbase = blockScanExcl(dtot[d], t, lw, &tot2);
    gput[d] = dbase + gh[d * nt + blockIdx.x] - ldig;
    wrun[d]       = ldig;
    wrun[256 + d] = ldig + c0;
    wrun[512 + d] = ldig + c0 + c1;
    wrun[768 + d] = ldig + c0 + c1 + c2;
  }
  __syncthreads();
  #pragma unroll
  for (int r = 0; r < 16; r++)
    stage[ wrun[w*256 + dg[r]] + rnk[r] ] = elems[r];
  __syncthreads();
  #pragma unroll
  for (int r = 0; r < 16; r++){
    unsigned j = (unsigned)r * 256u + t;
    uint64_t e = stage[j];
    unsigned d = (unsigned)((e >> shift) & 0xFF);
    unsigned dest = gput[d] + j;
    if (FINAL){
      if (dest < R_N){
        uint32_t key = (uint32_t)(e >> 32);
        fout[2u*dest]        = (float)(key >> 12);
        fout[2u*dest + 1u]   = (float)(key & 4095u);
        fout[2u*R_N + dest]  = __uint_as_float(~(uint32_t)e);
      }
    } else {
      out[dest] = e;
    }
  }
}

__global__ __launch_bounds__(256) void k_scatter(const uint64_t* __restrict__ in,
                                                 uint64_t* __restrict__ out,
                                                 unsigned shift,
                                                 const unsigned* __restrict__ gh,
                                                 const unsigned* __restrict__ dtot,
                                                 unsigned nt){
  scatter_body<false>(in, out, nullptr, shift, gh, dtot, nt);
}

__global__ __launch_bounds__(256) void k_scatter_out(const uint64_t* __restrict__ in,
                                                     float* __restrict__ fout,
                                                     unsigned shift,
                                                     const unsigned* __restrict__ gh,
                                                     const unsigned* __restrict__ dtot,
                                                     unsigned nt){
  scatter_body<true>(in, nullptr, fout, shift, gh, dtot, nt);
}

// Count real segment heads per 256-elem block (pad heads excluded -> total = U).
__global__ __launch_bounds__(256) void k_headcount(const uint64_t* __restrict__ in,
                                                   unsigned* __restrict__ hcnt){
  __shared__ unsigned wc[4];
  unsigned t = threadIdx.x, lane = t & 63u, w = t >> 6;
  size_t p = (size_t)blockIdx.x * 256 + t;
  uint64_t e = in[p];
  uint32_t k = (uint32_t)(e >> 32);
  bool head = ((p == 0) || ((uint32_t)(in[p-1] >> 32) != k)) && ((uint32_t)e != PAD_VAL);
  uint64_t m = __ballot(head);
  if (lane == 0) wc[w] = (unsigned)__popcll(m);
  __syncthreads();
  if (t == 0) hcnt[blockIdx.x] = wc[0] + wc[1] + wc[2] + wc[3];
}

// Fast single-block scan of NSB counts via u16 LDS staging; writes total.
__global__ __launch_bounds__(256) void k_scanheads(unsigned* __restrict__ hcnt,
                                                   unsigned* __restrict__ utot){
  __shared__ unsigned short buf[NSB];    // 34.4 KB
  __shared__ unsigned lw[4];
  unsigned t = threadIdx.x;
  for (unsigned i = t; i < NSB; i += 256) buf[i] = (unsigned short)hcnt[i];
  __syncthreads();
  const unsigned CH = (NSB + 255) / 256;
  unsigned s = 0;
  for (unsigned k = 0; k < CH; k++){
    unsigned i = t * CH + k;
    if (i < NSB) s += buf[i];
  }
  unsigned tot;
  unsigned carry = blockScanExcl(s, t, lw, &tot);
  for (unsigned k = 0; k < CH; k++){
    unsigned i = t * CH + k;
    if (i < NSB){ unsigned v = buf[i]; hcnt[i] = carry; carry += v; }
  }
  if (t == 0) utot[0] = tot;
}

// Sentinel-fill [*utot, grid-extent).
__global__ __launch_bounds__(256) void k_fill_tail(uint64_t* __restrict__ A,
                                                   const unsigned* __restrict__ utot){
  unsigned U = utot[0];
  unsigned i = blockIdx.x * 256u + threadIdx.x;
  if (i >= U) A[i] = ((uint64_t)PAD_KEY << 32) | (uint64_t)PAD_VAL;
}

// In-order segmented sum (fp32, original contribution order -> bit-identical
// to segment_sum). Candidates written dense, key-ascending. PURE round-2
// version: no histogram, no global atomics.
__global__ __launch_bounds__(256) void k_segsum(const uint64_t* __restrict__ in,
                                                uint64_t* __restrict__ out,
                                                const unsigned* __restrict__ hbase){
  __shared__ unsigned wc[4], woffs[4];
  unsigned t = threadIdx.x, lane = t & 63u, w = t >> 6;
  size_t p = (size_t)blockIdx.x * 256 + t;
  uint64_t e0 = in[p];
  uint32_t k = (uint32_t)(e0 >> 32);
  bool head = ((p == 0) || ((uint32_t)(in[p-1] >> 32) != k)) && ((uint32_t)e0 != PAD_VAL);
  uint64_t m = __ballot(head);
  if (lane == 0) wc[w] = (unsigned)__popcll(m);
  __syncthreads();
  if (t == 0){ unsigned a = 0; for (int i = 0; i < 4; i++){ woffs[i] = a; a += wc[i]; } }
  __syncthreads();
  if (head){
    uint64_t ltm = (lane == 0) ? 0ull : (~0ull >> (64u - lane));
    unsigned rank = (unsigned)__popcll(m & ltm);
    unsigned oidx = hbase[blockIdx.x] + woffs[w] + rank;
    float s = __uint_as_float((uint32_t)e0);
    size_t q = p + 1;
    while (q < NPAD){
      uint64_t e = in[q];
      if ((uint32_t)(e >> 32) != k) break;
      uint32_t vb = (uint32_t)e;
      if (vb == PAD_VAL) break;
      s += __uint_as_float(vb);
      q++;
    }
    out[oidx] = ((uint64_t)k << 32) | (uint64_t)(uint32_t)(~__float_as_uint(s));
  }
}

// ---- Radix-select (top-16 sortkey bits), atomic-free ---------------------
// Per-tile select histogram: stage 0 = sortkey top byte; stage 1 = second
// byte restricted to top byte == sel[0]. Same k_hist pattern (per-tile write).
__global__ __launch_bounds__(256) void k_selhist(const uint64_t* __restrict__ A,
                                                 unsigned* __restrict__ g,
                                                 const unsigned* __restrict__ sel,
                                                 int stage){
  __shared__ unsigned h[256];
  __shared__ unsigned bsh;
  unsigned t = threadIdx.x;
  h[t] = 0;
  if (t == 0) bsh = stage ? sel[0] : 0u;
  __syncthreads();
  unsigned bs = bsh;
  size_t base = (size_t)blockIdx.x * TILE;
  #pragma unroll
  for (int r = 0; r < 16; r++){
    uint32_t vb = (uint32_t)A[base + (size_t)r*256 + t];
    if (stage == 0) atomicAdd(&h[vb >> 24], 1u);
    else if ((vb >> 24) == bs) atomicAdd(&h[(vb >> 16) & 0xFFu], 1u);
  }
  __syncthreads();
  g[t * NTILES + blockIdx.x] = h[t];
}

// Fold per-tile rows: block b sums g[b][*] -> h[b]. 256 blocks.
__global__ __launch_bounds__(256) void k_fold(const unsigned* __restrict__ g,
                                              unsigned* __restrict__ h){
  __shared__ unsigned lw[4];
  unsigned b = blockIdx.x, t = threadIdx.x;
  unsigned s = 0;
  for (unsigned i = t; i < NTILES; i += 256) s += g[b * NTILES + i];
  unsigned tot;
  blockScanExcl(s, t, lw, &tot);
  if (t == 0) h[b] = tot;
}

// Pick threshold digit: smallest bin where cumulative (plus carried base)
// reaches R. stage 0 -> sel[0]=b*, sel[1]=cumExcl; stage 1 -> sel[2]=thr16.
__global__ __launch_bounds__(256) void k_pick(const unsigned* __restrict__ h,
                                              unsigned* __restrict__ sel, int stage){
  __shared__ unsigned lw[4];
  __shared__ unsigned esh[256];
  __shared__ unsigned fl[4];
  __shared__ unsigned basesh;
  unsigned t = threadIdx.x, lane = t & 63u, w = t >> 6;
  if (t == 0) basesh = stage ? sel[1] : 0u;
  __syncthreads();
  unsigned base = basesh;
  unsigned v = h[t];
  unsigned tot;
  unsigned e = blockScanExcl(v, t, lw, &tot);
  esh[t] = e;
  bool f = (base + e + v >= R_N);
  uint64_t m = __ballot(f);
  if (lane == 0)
    fl[w] = m ? (w*64u + (unsigned)__ffsll((unsigned long long)m) - 1u) : 0xFFFFFFFFu;
  __syncthreads();
  if (t == 0){
    unsigned bb = min(min(fl[0], fl[1]), min(fl[2], fl[3]));
    if (bb == 0xFFFFFFFFu) bb = 255u;
    if (stage == 0){ sel[0] = bb; sel[1] = esh[bb]; }
    else           { sel[2] = (sel[0] << 8) | bb; }
  }
}

// Count survivors (sk16 <= thr16) per 256-elem block.
__global__ __launch_bounds__(256) void k_cmpcount(const uint64_t* __restrict__ A,
                                                  const unsigned* __restrict__ sel,
                                                  unsigned* __restrict__ ccnt){
  __shared__ unsigned wc[4];
  __shared__ unsigned thr;
  unsigned t = threadIdx.x, lane = t & 63u, w = t >> 6;
  if (t == 0) thr = sel[2];
  __syncthreads();
  size_t p = (size_t)blockIdx.x * 256 + t;
  bool q = (((uint32_t)A[p]) >> 16) <= thr;
  uint64_t m = __ballot(q);
  if (lane == 0) wc[w] = (unsigned)__popcll(m);
  __syncthreads();
  if (t == 0) ccnt[blockIdx.x] = wc[0] + wc[1] + wc[2] + wc[3];
}

// Stable compaction of survivors into B[0, M). Order preserved = key-ascending.
__global__ __launch_bounds__(256) void k_compact(const uint64_t* __restrict__ A,
                                                 uint64_t* __restrict__ B,
                                                 const unsigned* __restrict__ sel,
                                                 const unsigned* __restrict__ cbase){
  __shared__ unsigned wc[4], woffs[4];
  __shared__ unsigned thr;
  unsigned t = threadIdx.x, lane = t & 63u, w = t >> 6;
  if (t == 0) thr = sel[2];
  __syncthreads();
  size_t p = (size_t)blockIdx.x * 256 + t;
  uint64_t e = A[p];
  bool q = (((uint32_t)e) >> 16) <= thr;
  uint64_t m = __ballot(q);
  if (lane == 0) wc[w] = (unsigned)__popcll(m);
  __syncthreads();
  if (t == 0){ unsigned a = 0; for (int i = 0; i < 4; i++){ woffs[i] = a; a += wc[i]; } }
  __syncthreads();
  if (q){
    uint64_t ltm = (lane == 0) ? 0ull : (~0ull >> (64u - lane));
    unsigned rank = (unsigned)__popcll(m & ltm);
    unsigned dest = cbase[blockIdx.x] + woffs[w] + rank;
    if (dest < SPAD) B[dest] = e;        // guard (margin ~24%, never expected)
  }
}

extern "C" void kernel_launch(void* const* d_in, const int* in_sizes, int n_in,
                              void* d_out, int out_size, void* d_ws, size_t ws_size,
                              hipStream_t stream) {
  const int*   sidx = (const int*)d_in[0];
  const int*   ridx = (const int*)d_in[1];
  const float* rval = (const float*)d_in[2];
  const float* grad = (const float*)d_in[3];
  float* out = (float*)d_out;

  uint64_t* A0   = (uint64_t*)d_ws;                       // 35.3 MB
  uint64_t* A1   = A0 + NPAD;                             // 35.3 MB
  unsigned* gh   = (unsigned*)(A1 + NPAD);                // 256*NTILES = 1.1 MB
  unsigned* dtot = gh + 256 * NTILES;                     // 1 KB
  unsigned* hcnt = dtot + 256;                            // 67 KB
  unsigned* utot = hcnt + NSB;                            // 4 B
  unsigned* hsel = utot + 1;                              // 1 KB
  unsigned* sel  = hsel + 256;                            // 16 B
  unsigned* ccnt = sel + 4;                               // 67 KB
  unsigned* mtot = ccnt + NSB;                            // 4 B

  k_build<<<NSB, 256, 0, stream>>>(sidx, ridx, rval, grad, A0);

  // Stable key sort: 24 bits, 3 x 8-bit passes. A0->A1->A0->A1.
  k_hist    <<<NTILES, 256, 0, stream>>>(A0, 32, gh, NTILES);
  k_scanrows<<<256,    256, 0, stream>>>(gh, dtot, NTILES);
  k_scatter <<<NTILES, 256, 0, stream>>>(A0, A1, 32, gh, dtot, NTILES);
  k_hist    <<<NTILES, 256, 0, stream>>>(A1, 40, gh, NTILES);
  k_scanrows<<<256,    256, 0, stream>>>(gh, dtot, NTILES);
  k_scatter <<<NTILES, 256, 0, stream>>>(A1, A0, 40, gh, dtot, NTILES);
  k_hist    <<<NTILES, 256, 0, stream>>>(A0, 48, gh, NTILES);
  k_scanrows<<<256,    256, 0, stream>>>(gh, dtot, NTILES);
  k_scatter <<<NTILES, 256, 0, stream>>>(A0, A1, 48, gh, dtot, NTILES);

  // Coalesce (candidates key-ascending in A0).
  k_headcount<<<NSB, 256, 0, stream>>>(A1, hcnt);
  k_scanheads<<<1,   256, 0, stream>>>(hcnt, utot);
  k_fill_tail<<<NSB, 256, 0, stream>>>(A0, utot);
  k_segsum   <<<NSB, 256, 0, stream>>>(A1, A0, hcnt);

  // Radix-select threshold on top-16 sortkey bits (atomic-free two-stage),
  // then stable compaction A0 -> A1[0, M), sentinel-fill [M, SPAD).
  k_selhist  <<<NTILES, 256, 0, stream>>>(A0, gh, sel, 0);
  k_fold     <<<256,    256, 0, stream>>>(gh, hsel);
  k_pick     <<<1,      256, 0, stream>>>(hsel, sel, 0);
  k_selhist  <<<NTILES, 256, 0, stream>>>(A0, gh, sel, 1);
  k_fold     <<<256,    256, 0, stream>>>(gh, hsel);
  k_pick     <<<1,      256, 0, stream>>>(hsel, sel, 1);
  k_cmpcount <<<NSB, 256, 0, stream>>>(A0, sel, ccnt);
  k_scanheads<<<1,   256, 0, stream>>>(ccnt, mtot);
  k_compact  <<<NSB, 256, 0, stream>>>(A0, A1, sel, ccnt);
  k_fill_tail<<<SPAD/256, 256, 0, stream>>>(A1, mtot);

  // Stable value sort on survivors: 4 x 8-bit passes, final fused with output.
  // A1->A0->A1->A0->out.
  k_hist    <<<NT2, 256, 0, stream>>>(A1, 0, gh, NT2);
  k_scanrows<<<256, 256, 0, stream>>>(gh, dtot, NT2);
  k_scatter <<<NT2, 256, 0, stream>>>(A1, A0, 0, gh, dtot, NT2);
  k_hist    <<<NT2, 256, 0, stream>>>(A0, 8, gh, NT2);
  k_scanrows<<<256, 256, 0, stream>>>(gh, dtot, NT2);
  k_scatter <<<NT2, 256, 0, stream>>>(A0, A1, 8, gh, dtot, NT2);
  k_hist    <<<NT2, 256, 0, stream>>>(A1, 16, gh, NT2);
  k_scanrows<<<256, 256, 0, stream>>>(gh, dtot, NT2);
  k_scatter <<<NT2, 256, 0, stream>>>(A1, A0, 16, gh, dtot, NT2);
  k_hist       <<<NT2, 256, 0, stream>>>(A0, 24, gh, NT2);
  k_scanrows   <<<256, 256, 0, stream>>>(gh, dtot, NT2);
  k_scatter_out<<<NT2, 256, 0, stream>>>(A0, out, 24, gh, dtot, NT2);
}